// Round 6
// baseline (367.574 us; speedup 1.0000x reference)
//
#include <hip/hip_runtime.h>
#include <hip/hip_bf16.h>

#define B_  32
#define T_  2048
#define DH_ 1024
#define DS_ 1024
#define A_  512
#define M_  (B_ * T_)   // 65536

typedef __attribute__((ext_vector_type(8))) short bf16x8;
typedef __attribute__((ext_vector_type(4))) float f32x4;

__device__ __forceinline__ unsigned short f2bf(float f) {
    union { float f; unsigned u; } v; v.f = f;
    unsigned r = 0x7FFFu + ((v.u >> 16) & 1u);
    return (unsigned short)((v.u + r) >> 16);
}
__device__ __forceinline__ float bflo(unsigned u) {
    union { unsigned u; float f; } v; v.u = u << 16; return v.f;
}
__device__ __forceinline__ float bfhi(unsigned u) {
    union { unsigned u; float f; } v; v.u = u & 0xFFFF0000u; return v.f;
}
__device__ __forceinline__ float fast_tanh(float x) {
    float cx = fminf(fmaxf(x, -9.f), 9.f);
    float e2 = __expf(2.f * cx);
    return (e2 - 1.f) / (e2 + 1.f);
}

// ---- zero e [M_] and c [B_*DH_] ------------------------------------------
__global__ void zero_kernel(float* __restrict__ e, float* __restrict__ c) {
    int i = blockIdx.x * blockDim.x + threadIdx.x;
    if (i < M_) e[i] = 0.f;
    int j = i - M_;
    if (j >= 0 && j < B_ * DH_) c[j] = 0.f;
}

// ---- U_t[a][k] = bf16(U_a[k][a]) -----------------------------------------
__global__ void prep_ut(const float* __restrict__ U, unsigned short* __restrict__ Ut) {
    int o = blockIdx.x * 256 + threadIdx.x;
    int a = o >> 10, k = o & (DH_ - 1);
    Ut[o] = f2bf(U[k * A_ + a]);
}

// ---- Ws[b][a] = s[b,:] . W_a[:,a] ----------------------------------------
__global__ void ws_gemv(const float* __restrict__ s, const float* __restrict__ W,
                        float* __restrict__ Ws) {
    int idx = blockIdx.x * 256 + threadIdx.x;
    int b = idx >> 9, a = idx & (A_ - 1);
    const float* sp = s + b * DS_;
    float acc = 0.f;
#pragma unroll 4
    for (int k = 0; k < DS_; ++k) acc += sp[k] * W[k * A_ + a];
    Ws[idx] = acc;
}

// ---- main GEMM: m97 geometry. 128x128, BK=32, 4 waves, 32 KiB LDS dbuf,
// linear LDS, B via global_load_lds w=16, A reg-staged f32->bf16 (fused
// conversion, tn==0 emits hb). XCD-chunked bid swizzle. ~4 blocks/CU.
__global__ void __launch_bounds__(256, 4)
gemm_m97(const float* __restrict__ h,
         const unsigned short* __restrict__ Ut,
         const float* __restrict__ Ws, const float* __restrict__ va,
         float* __restrict__ e, unsigned short* __restrict__ hb) {
    __shared__ unsigned short As[2][128][32];   // 8 KB per buf
    __shared__ unsigned short Bs[2][128][32];

    const int tid = threadIdx.x;
    // XCD-chunk swizzle: nwg = 2048, 256 wg/XCD; 4 tn-sharers consecutive
    const int bid0 = blockIdx.x;
    const int bid = (bid0 & 7) * 256 + (bid0 >> 3);
    const int tn = bid & 3, tm = bid >> 2;
    const int rowBase = tm * 128, nBase = tn * 128;
    const bool writeHb = (tn == 0);

    const int lane = tid & 63;
    const int wid = tid >> 6;                   // 4 waves: 2(M) x 2(N)
    const int wm = wid >> 1, wn = wid & 1;      // wave tile 64x64
    const int lr = lane & 15, kg = lane >> 4;

    // A staging: 128 rows x 32 f32; thread covers rows j*32 + tid/8, 4 f32
    const int aRow = tid >> 3;                  // 0..31
    const int aColF = (tid & 7) * 4;            // f32 col 0..28

    f32x4 acc[4][4];
#pragma unroll
    for (int i = 0; i < 4; ++i)
#pragma unroll
        for (int j = 0; j < 4; ++j) acc[i][j] = (f32x4){0.f, 0.f, 0.f, 0.f};

    auto stageB = [&](int buf, int kt) {
        const int k0 = kt * 32;
#pragma unroll
        for (int q = 0; q < 2; ++q) {
            int b = q * 4096 + tid * 16;        // byte offset in 8 KB tile
            int r = b >> 6;                     // row 0..127
            int col = (b & 63) >> 1;            // bf16 col
            const unsigned short* gb = Ut + (size_t)(nBase + r) * DH_ + k0 + col;
            __builtin_amdgcn_global_load_lds(
                (const __attribute__((address_space(1))) unsigned int*)gb,
                (__attribute__((address_space(3))) unsigned int*)(&Bs[buf][0][0] + (b >> 1)),
                16, 0, 0);
        }
    };

    auto loadA = [&](float4* areg, int kt) {
        const int k0 = kt * 32;
#pragma unroll
        for (int j = 0; j < 4; ++j) {
            int row = j * 32 + aRow;
            areg[j] = *(const float4*)(h + (size_t)(rowBase + row) * DH_ + k0 + aColF);
        }
    };

    auto writeA = [&](const float4* areg, int buf, int kt) {
        const int k0 = kt * 32;
#pragma unroll
        for (int j = 0; j < 4; ++j) {
            int row = j * 32 + aRow;
            ushort4 u;
            u.x = f2bf(areg[j].x); u.y = f2bf(areg[j].y);
            u.z = f2bf(areg[j].z); u.w = f2bf(areg[j].w);
            *(ushort4*)(&As[buf][row][aColF]) = u;
            if (writeHb)
                *(ushort4*)(hb + (size_t)(rowBase + row) * DH_ + k0 + aColF) = u;
        }
    };

    float4 areg[4];
    stageB(0, 0);
    loadA(areg, 0);
    writeA(areg, 0, 0);
    __syncthreads();

#pragma unroll 1
    for (int kt = 0; kt < DH_ / 32; ++kt) {
        const int buf = kt & 1;
        const bool more = (kt < DH_ / 32 - 1);
        if (more) {
            stageB(buf ^ 1, kt + 1);
            loadA(areg, kt + 1);
        }

        bf16x8 af[4], bq[4];
#pragma unroll
        for (int mi = 0; mi < 4; ++mi)
            af[mi] = *(const bf16x8*)(&As[buf][wm * 64 + mi * 16 + lr][kg * 8]);
#pragma unroll
        for (int nf = 0; nf < 4; ++nf)
            bq[nf] = *(const bf16x8*)(&Bs[buf][wn * 64 + nf * 16 + lr][kg * 8]);
#pragma unroll
        for (int mi = 0; mi < 4; ++mi)
#pragma unroll
            for (int nf = 0; nf < 4; ++nf)
                acc[mi][nf] = __builtin_amdgcn_mfma_f32_16x16x32_bf16(
                    af[mi], bq[nf], acc[mi][nf], 0, 0, 0);

        if (more) writeA(areg, buf ^ 1, kt + 1);
        __syncthreads();
    }

    // epilogue: e[row] += sum_a tanh(acc + Ws[b][a]) * v[a]
    const int bIdx = rowBase >> 11;
    const float* WsRow = Ws + bIdx * A_;
    float wsv[4], vav[4];
#pragma unroll
    for (int nf = 0; nf < 4; ++nf) {
        int a = nBase + wn * 64 + nf * 16 + lr;
        wsv[nf] = WsRow[a];
        vav[nf] = va[a];
    }
#pragma unroll
    for (int mi = 0; mi < 4; ++mi) {
#pragma unroll
        for (int j = 0; j < 4; ++j) {
            float ssum = 0.f;
#pragma unroll
            for (int nf = 0; nf < 4; ++nf) {
                float x = acc[mi][nf][j] + wsv[nf];
                ssum += fast_tanh(x) * vav[nf];
            }
            ssum += __shfl_xor(ssum, 1);
            ssum += __shfl_xor(ssum, 2);
            ssum += __shfl_xor(ssum, 4);
            ssum += __shfl_xor(ssum, 8);
            if (lr == 0) {
                int row = rowBase + wm * 64 + mi * 16 + kg * 4 + j;
                atomicAdd(&e[row], ssum);
            }
        }
    }
}

// ---- softmax over T per batch (in place on e) ----------------------------
__global__ void softmax_kernel(float* __restrict__ e) {
    __shared__ float red[8];
    const int b = blockIdx.x, tid = threadIdx.x;
    float* ep = e + b * T_;
    float4 v0 = ((float4*)ep)[tid * 2];
    float4 v1 = ((float4*)ep)[tid * 2 + 1];
    float m = fmaxf(fmaxf(fmaxf(v0.x, v0.y), fmaxf(v0.z, v0.w)),
                    fmaxf(fmaxf(v1.x, v1.y), fmaxf(v1.z, v1.w)));
#pragma unroll
    for (int off = 1; off < 64; off <<= 1) m = fmaxf(m, __shfl_xor(m, off));
    int wid = tid >> 6;
    if ((tid & 63) == 0) red[wid] = m;
    __syncthreads();
    m = fmaxf(fmaxf(red[0], red[1]), fmaxf(red[2], red[3]));
    v0.x = __expf(v0.x - m); v0.y = __expf(v0.y - m);
    v0.z = __expf(v0.z - m); v0.w = __expf(v0.w - m);
    v1.x = __expf(v1.x - m); v1.y = __expf(v1.y - m);
    v1.z = __expf(v1.z - m); v1.w = __expf(v1.w - m);
    float ssum = v0.x + v0.y + v0.z + v0.w + v1.x + v1.y + v1.z + v1.w;
#pragma unroll
    for (int off = 1; off < 64; off <<= 1) ssum += __shfl_xor(ssum, off);
    if ((tid & 63) == 0) red[4 + wid] = ssum;
    __syncthreads();
    float inv = 1.f / (red[4] + red[5] + red[6] + red[7]);
    v0.x *= inv; v0.y *= inv; v0.z *= inv; v0.w *= inv;
    v1.x *= inv; v1.y *= inv; v1.z *= inv; v1.w *= inv;
    ((float4*)ep)[tid * 2] = v0;
    ((float4*)ep)[tid * 2 + 1] = v1;
}

// ---- c[b][d] = sum_t a[b][t] * hb[b][t][d]  (bf16 h) ----------------------
__global__ void ctx_bf(const unsigned int* __restrict__ hb, const float* __restrict__ a,
                       float* __restrict__ c) {
    const int bid = blockIdx.x;
    const int b = bid >> 5, seg = bid & 31;
    const int tid = threadIdx.x;
    const int half = tid >> 7;                 // 0/1 interleaved t
    const int d0 = (tid & 127) * 8;
    const int t0 = seg * 64 + half;
    float acc[8] = {0.f, 0.f, 0.f, 0.f, 0.f, 0.f, 0.f, 0.f};
    const unsigned int* hp = hb + (((size_t)b * T_ + t0) * DH_ + d0) / 2;
    const float* ap = a + (size_t)b * T_ + t0;
#pragma unroll 4
    for (int t = 0; t < 64; t += 2) {
        float w = ap[t];
        uint4 v = *(const uint4*)(hp + (size_t)t * (DH_ / 2));
        acc[0] += w * bflo(v.x); acc[1] += w * bfhi(v.x);
        acc[2] += w * bflo(v.y); acc[3] += w * bfhi(v.y);
        acc[4] += w * bflo(v.z); acc[5] += w * bfhi(v.z);
        acc[6] += w * bflo(v.w); acc[7] += w * bfhi(v.w);
    }
    float* cp = c + (size_t)b * DH_ + d0;
#pragma unroll
    for (int j = 0; j < 8; ++j) atomicAdd(cp + j, acc[j]);
}

extern "C" void kernel_launch(void* const* d_in, const int* in_sizes, int n_in,
                              void* d_out, int out_size, void* d_ws, size_t ws_size,
                              hipStream_t stream) {
    const float* s   = (const float*)d_in[0];
    const float* h   = (const float*)d_in[1];
    const float* W_a = (const float*)d_in[2];
    const float* U_a = (const float*)d_in[3];
    const float* v_a = (const float*)d_in[4];
    float* c = (float*)d_out;

    // workspace layout (bytes): e | Ws | Ut | hb   (~129.3 MB)
    const size_t off_Ws = (size_t)M_ * 4;
    const size_t off_Ut = off_Ws + (size_t)B_ * A_ * 4;
    const size_t off_hb = off_Ut + (size_t)A_ * DH_ * 2;

    float* e  = (float*)d_ws;
    float* Ws = (float*)((char*)d_ws + off_Ws);
    unsigned short* Ut = (unsigned short*)((char*)d_ws + off_Ut);
    unsigned short* hb = (unsigned short*)((char*)d_ws + off_hb);

    zero_kernel<<<(M_ + B_ * DH_ + 255) / 256, 256, 0, stream>>>(e, c);
    prep_ut<<<(A_ * DH_) / 256, 256, 0, stream>>>(U_a, Ut);
    ws_gemv<<<(B_ * A_) / 256, 256, 0, stream>>>(s, W_a, Ws);
    gemm_m97<<<(M_ / 128) * (A_ / 128), 256, 0, stream>>>(h, Ut, Ws, v_a, e, hb);
    softmax_kernel<<<B_, 256, 0, stream>>>(e);
    ctx_bf<<<B_ * 32, 256, 0, stream>>>((const unsigned int*)hb, e, c);
}

// Round 7
// 199.657 us; speedup vs baseline: 1.8410x; 1.8410x over previous
//
#include <hip/hip_runtime.h>
#include <hip/hip_bf16.h>

#define B_  32
#define T_  2048
#define DH_ 1024
#define DS_ 1024
#define A_  512
#define M_  (B_ * T_)   // 65536

typedef __attribute__((ext_vector_type(8))) short bf16x8;
typedef __attribute__((ext_vector_type(4))) float f32x4;

__device__ __forceinline__ unsigned short f2bf(float f) {
    union { float f; unsigned u; } v; v.f = f;
    unsigned r = 0x7FFFu + ((v.u >> 16) & 1u);
    return (unsigned short)((v.u + r) >> 16);
}
__device__ __forceinline__ float fast_tanh(float x) {
    float cx = fminf(fmaxf(x, -9.f), 9.f);
    float e2 = __expf(2.f * cx);
    return (e2 - 1.f) / (e2 + 1.f);
}
// pack two f32 -> two bf16 (round-half-up: +0x8000 then take high16)
__device__ __forceinline__ unsigned pack_bf2(float lo, float hi) {
    union { float f; unsigned u; } a, b;
    a.f = lo; b.f = hi;
    return __builtin_amdgcn_perm(b.u + 0x8000u, a.u + 0x8000u, 0x07060302u);
}

// ---- zero e [M_] ---------------------------------------------------------
__global__ void zero_e(float* __restrict__ e) {
    e[blockIdx.x * 256 + threadIdx.x] = 0.f;
}

// ---- U_t[a][k] = bf16(U_a[k][a]) -----------------------------------------
__global__ void prep_ut(const float* __restrict__ U, unsigned short* __restrict__ Ut) {
    int o = blockIdx.x * 256 + threadIdx.x;
    int a = o >> 10, k = o & (DH_ - 1);
    Ut[o] = f2bf(U[k * A_ + a]);
}

// ---- Ws[b][a] = s[b,:] . W_a[:,a]  (k-split 4-way + LDS reduce) ----------
__global__ void ws_gemv2(const float* __restrict__ s, const float* __restrict__ W,
                         float* __restrict__ Ws) {
    __shared__ float red[4][64];
    const int blk = blockIdx.x;            // 256 = b*8 + aseg
    const int b = blk >> 3, a0 = (blk & 7) * 64;
    const int tid = threadIdx.x;
    const int a = a0 + (tid & 63), kq = tid >> 6;   // 4 k-quarters
    const float* sp = s + b * DS_ + kq * 256;
    const float* wp = W + (size_t)(kq * 256) * A_ + a;
    float acc = 0.f;
#pragma unroll 8
    for (int k = 0; k < 256; ++k) acc += sp[k] * wp[(size_t)k * A_];
    red[kq][tid & 63] = acc;
    __syncthreads();
    if (tid < 64)
        Ws[b * A_ + a0 + tid] = red[0][tid] + red[1][tid] + red[2][tid] + red[3][tid];
}

// ---- main GEMM: 128x128, BK=32, 4 waves; A reg-staged f32 with cheap
// add+perm bf16 pack into PADDED As[128][40]; B via global_load_lds linear.
// XCD-chunked bid swizzle; atomicAdd e epilogue (tanh + v reduction fused).
__global__ void __launch_bounds__(256, 4)
gemm_e3(const float* __restrict__ h,
        const unsigned short* __restrict__ Ut,
        const float* __restrict__ Ws, const float* __restrict__ va,
        float* __restrict__ e) {
    __shared__ unsigned short As[2][128][40];   // padded (ds_write staged)
    __shared__ unsigned short Bs[2][128][32];   // linear (gls destination)

    const int tid = threadIdx.x;
    // XCD-chunk swizzle: nwg = 2048, 256 wg/XCD; 4 tn-sharers same XCD
    const int bid0 = blockIdx.x;
    const int bid = (bid0 & 7) * 256 + (bid0 >> 3);
    const int tn = bid & 3, tm = bid >> 2;
    const int rowBase = tm * 128, nBase = tn * 128;

    const int lane = tid & 63;
    const int wid = tid >> 6;                   // 4 waves: 2(M) x 2(N)
    const int wm = wid >> 1, wn = wid & 1;      // wave tile 64x64
    const int lr = lane & 15, kg = lane >> 4;

    const int aRow = tid >> 3;                  // 0..31
    const int aColF = (tid & 7) * 4;            // f32 col 0..28

    f32x4 acc[4][4];
#pragma unroll
    for (int i = 0; i < 4; ++i)
#pragma unroll
        for (int j = 0; j < 4; ++j) acc[i][j] = (f32x4){0.f, 0.f, 0.f, 0.f};

    auto stageB = [&](int buf, int kt) {
        const int k0 = kt * 32;
#pragma unroll
        for (int q = 0; q < 2; ++q) {
            int b = q * 4096 + tid * 16;        // byte offset in 8 KB tile
            int r = b >> 6;
            int col = (b & 63) >> 1;
            const unsigned short* gb = Ut + (size_t)(nBase + r) * DH_ + k0 + col;
            __builtin_amdgcn_global_load_lds(
                (const __attribute__((address_space(1))) unsigned int*)gb,
                (__attribute__((address_space(3))) unsigned int*)(&Bs[buf][0][0] + (b >> 1)),
                16, 0, 0);
        }
    };

    auto loadA = [&](float4* areg, int kt) {
        const int k0 = kt * 32;
#pragma unroll
        for (int j = 0; j < 4; ++j) {
            int row = j * 32 + aRow;
            areg[j] = *(const float4*)(h + (size_t)(rowBase + row) * DH_ + k0 + aColF);
        }
    };

    auto writeA = [&](const float4* areg, int buf) {
#pragma unroll
        for (int j = 0; j < 4; ++j) {
            int row = j * 32 + aRow;
            uint2 u;
            u.x = pack_bf2(areg[j].x, areg[j].y);
            u.y = pack_bf2(areg[j].z, areg[j].w);
            *(uint2*)(&As[buf][row][aColF]) = u;
        }
    };

    float4 areg[4];
    stageB(0, 0);
    loadA(areg, 0);
    writeA(areg, 0);
    __syncthreads();

#pragma unroll 1
    for (int kt = 0; kt < DH_ / 32; ++kt) {
        const int buf = kt & 1;
        const bool more = (kt < DH_ / 32 - 1);
        if (more) {
            stageB(buf ^ 1, kt + 1);
            loadA(areg, kt + 1);
        }

        bf16x8 af[4], bq[4];
#pragma unroll
        for (int mi = 0; mi < 4; ++mi)
            af[mi] = *(const bf16x8*)(&As[buf][wm * 64 + mi * 16 + lr][kg * 8]);
#pragma unroll
        for (int nf = 0; nf < 4; ++nf)
            bq[nf] = *(const bf16x8*)(&Bs[buf][wn * 64 + nf * 16 + lr][kg * 8]);
#pragma unroll
        for (int mi = 0; mi < 4; ++mi)
#pragma unroll
            for (int nf = 0; nf < 4; ++nf)
                acc[mi][nf] = __builtin_amdgcn_mfma_f32_16x16x32_bf16(
                    af[mi], bq[nf], acc[mi][nf], 0, 0, 0);

        if (more) writeA(areg, buf ^ 1);
        __syncthreads();
    }

    // epilogue: e[row] += sum_a tanh(acc + Ws[b][a]) * v[a]
    const int bIdx = rowBase >> 11;
    const float* WsRow = Ws + bIdx * A_;
    float wsv[4], vav[4];
#pragma unroll
    for (int nf = 0; nf < 4; ++nf) {
        int a = nBase + wn * 64 + nf * 16 + lr;
        wsv[nf] = WsRow[a];
        vav[nf] = va[a];
    }
#pragma unroll
    for (int mi = 0; mi < 4; ++mi) {
#pragma unroll
        for (int j = 0; j < 4; ++j) {
            float ssum = 0.f;
#pragma unroll
            for (int nf = 0; nf < 4; ++nf) {
                float x = acc[mi][nf][j] + wsv[nf];
                ssum += fast_tanh(x) * vav[nf];
            }
            ssum += __shfl_xor(ssum, 1);
            ssum += __shfl_xor(ssum, 2);
            ssum += __shfl_xor(ssum, 4);
            ssum += __shfl_xor(ssum, 8);
            if (lr == 0) {
                int row = rowBase + wm * 64 + mi * 16 + kg * 4 + j;
                atomicAdd(&e[row], ssum);
            }
        }
    }
}

// ---- fused softmax + context: block = (b, dseg of 128) -------------------
// Redundant per-block softmax on e[b,:] (L2-hot, cheap), then weighted sum
// over f32 h for this block's 128-column d-slice; direct store to c.
__global__ void smax_ctx(const float* __restrict__ e, const float* __restrict__ h,
                         float* __restrict__ c) {
    __shared__ float al[T_];        // exp(e - m), unnormalized
    __shared__ float red[8];
    __shared__ float part[256];
    const int b = blockIdx.x >> 3, dseg = blockIdx.x & 7;
    const int tid = threadIdx.x;
    const float* ep = e + (size_t)b * T_;

    float4 v0 = ((const float4*)ep)[tid * 2];
    float4 v1 = ((const float4*)ep)[tid * 2 + 1];
    float m = fmaxf(fmaxf(fmaxf(v0.x, v0.y), fmaxf(v0.z, v0.w)),
                    fmaxf(fmaxf(v1.x, v1.y), fmaxf(v1.z, v1.w)));
#pragma unroll
    for (int off = 1; off < 64; off <<= 1) m = fmaxf(m, __shfl_xor(m, off));
    const int wv = tid >> 6;
    if ((tid & 63) == 0) red[wv] = m;
    __syncthreads();
    m = fmaxf(fmaxf(red[0], red[1]), fmaxf(red[2], red[3]));
    float e0 = __expf(v0.x - m), e1 = __expf(v0.y - m);
    float e2 = __expf(v0.z - m), e3 = __expf(v0.w - m);
    float e4 = __expf(v1.x - m), e5 = __expf(v1.y - m);
    float e6 = __expf(v1.z - m), e7 = __expf(v1.w - m);
    float ssum = e0 + e1 + e2 + e3 + e4 + e5 + e6 + e7;
#pragma unroll
    for (int off = 1; off < 64; off <<= 1) ssum += __shfl_xor(ssum, off);
    if ((tid & 63) == 0) red[4 + wv] = ssum;
    al[tid * 8 + 0] = e0; al[tid * 8 + 1] = e1;
    al[tid * 8 + 2] = e2; al[tid * 8 + 3] = e3;
    al[tid * 8 + 4] = e4; al[tid * 8 + 5] = e5;
    al[tid * 8 + 6] = e6; al[tid * 8 + 7] = e7;
    __syncthreads();
    const float inv = 1.f / (red[4] + red[5] + red[6] + red[7]);

    // context for d-slice
    const int d = dseg * 128 + (tid & 127);
    const int th = tid >> 7;                    // 2 t-streams
    const float* hp = h + ((size_t)b * T_ + th) * DH_ + d;
    float acc = 0.f;
#pragma unroll 8
    for (int t = 0; t < T_ / 2; ++t)
        acc += al[2 * t + th] * hp[(size_t)(2 * t) * DH_];
    part[tid] = acc;
    __syncthreads();
    if (tid < 128)
        c[(size_t)b * DH_ + dseg * 128 + tid] = (part[tid] + part[tid + 128]) * inv;
}

extern "C" void kernel_launch(void* const* d_in, const int* in_sizes, int n_in,
                              void* d_out, int out_size, void* d_ws, size_t ws_size,
                              hipStream_t stream) {
    const float* s   = (const float*)d_in[0];
    const float* h   = (const float*)d_in[1];
    const float* W_a = (const float*)d_in[2];
    const float* U_a = (const float*)d_in[3];
    const float* v_a = (const float*)d_in[4];
    float* c = (float*)d_out;

    // workspace: e [65536 f32] | Ws [16384 f32] | Ut [524288 bf16]  (~1.3 MB)
    float* e  = (float*)d_ws;
    float* Ws = e + M_;
    unsigned short* Ut = (unsigned short*)(Ws + B_ * A_);

    zero_e<<<M_ / 256, 256, 0, stream>>>(e);
    prep_ut<<<(A_ * DH_) / 256, 256, 0, stream>>>(U_a, Ut);
    ws_gemv2<<<B_ * 8, 256, 0, stream>>>(s, W_a, Ws);
    gemm_e3<<<(M_ / 128) * (A_ / 128), 256, 0, stream>>>(h, Ut, Ws, v_a, e);
    smax_ctx<<<B_ * 8, 256, 0, stream>>>(e, h, c);
}